// Round 2
// baseline (558.177 us; speedup 1.0000x reference)
//
#include <hip/hip_runtime.h>

#define BB 8192
#define DD 2048
#define NSLOT 7
#define NP1 (BB + 2*256)   // 8704 (256-aligned groups)
#define NP2 (BB + 4*256)   // 9216

typedef unsigned short u16;
typedef unsigned int   u32;
typedef unsigned long long u64;

typedef __bf16 bf16x8 __attribute__((ext_vector_type(8)));
typedef float  f32x4  __attribute__((ext_vector_type(4)));
typedef u16    u16x8  __attribute__((ext_vector_type(8)));

// ---- workspace layout (bytes). h1 reuses the xb region (xb dead after stage0).
#define OFF_WT   0ull
#define OFF_XB   (OFF_WT + (size_t)NSLOT*DD*DD*2)    // 58,720,256
#define OFF_H0   (OFF_XB + (size_t)BB*DD*2)          // 92,274,688
#define OFF_P1   (OFF_H0 + (size_t)BB*DD*2)          // 125,829,120
#define OFF_P2   (OFF_P1 + (size_t)NP1*4)
#define OFF_META (OFF_P2 + (size_t)NP2*4)
// meta ints: [12..14] bases1, [15..19] bases2, [20] input-is-bf16 flag

__device__ __forceinline__ u16 f2bf(float f) {
  u32 u = __float_as_uint(f);
  u32 r = (u + 0x7FFFu + ((u >> 16) & 1u)) >> 16;
  return (u16)r;
}
__device__ __forceinline__ float bf2f(u16 u) {
  return __uint_as_float(((u32)u) << 16);
}

__device__ __forceinline__ void gld16(const void* g, void* l) {
  __builtin_amdgcn_global_load_lds(
      (const __attribute__((address_space(1))) void*)g,
      (__attribute__((address_space(3))) void*)l, 16, 0, 0);
}

// ---------------- setup kernels ----------------

// Decide whether buffers are bf16-stored or fp32-stored.
__global__ void k_detect(const u16* x, int* meta) {
  __shared__ int cnt, cntz;
  if (threadIdx.x == 0) { cnt = 0; cntz = 0; }
  __syncthreads();
  u16 u = x[threadIdx.x * 17];       // odd stride mixes both parities
  int ex = (u >> 7) & 0xFF;
  int sane = (ex == 0) || (ex >= 112 && ex <= 143);
  atomicAdd(&cnt, sane);
  atomicAdd(&cntz, (u == 0) ? 1 : 0);
  __syncthreads();
  if (threadIdx.x == 0) meta[20] = (cnt >= 205 && cntz < 64) ? 1 : 0;
}

// Single-block routing: count via wave ballots (LDS atomics once per wave),
// 256-align group bases (GEMM tile BM=256), fill perms with ballot-prefix
// slot assignment.
__global__ __launch_bounds__(1024) void k_route(const int* __restrict__ pm,
                                                int* __restrict__ p1,
                                                int* __restrict__ p2,
                                                int* __restrict__ meta) {
  __shared__ int cnt[6];            // [0..1] stage1, [2..5] stage2
  __shared__ int cur[6];
  __shared__ int base1[2], base2[4];
  const int tid = threadIdx.x;
  const int lane = tid & 63;
  if (tid < 6) { cnt[tid] = 0; cur[tid] = 0; }
  __syncthreads();

  for (int i = tid; i < NP1; i += 1024) p1[i] = -1;
  for (int i = tid; i < NP2; i += 1024) p2[i] = -1;

  int myb0[8], myleaf[8];
  #pragma unroll
  for (int i = 0; i < 8; ++i) {
    int b = i * 1024 + tid;
    int b0 = pm[b*3] & 1, b1 = pm[b*3+1] & 1;
    myb0[i] = b0; myleaf[i] = b0*2 + b1;
  }
  #pragma unroll
  for (int i = 0; i < 8; ++i) {
    u64 m0 = __ballot(myb0[i] == 0);
    if (lane == 0) {
      atomicAdd(&cnt[0], __popcll(m0));
      atomicAdd(&cnt[1], 64 - __popcll(m0));
    }
    #pragma unroll
    for (int e = 0; e < 4; ++e) {
      u64 me = __ballot(myleaf[i] == e);
      if (lane == 0) atomicAdd(&cnt[2+e], __popcll(me));
    }
  }
  __syncthreads();
  if (tid == 0) {
    base1[0] = 0;
    base1[1] = (cnt[0] + 255) & ~255;
    meta[12] = 0; meta[13] = base1[1];
    meta[14] = base1[1] + ((cnt[1] + 255) & ~255);
    int b = 0;
    #pragma unroll
    for (int e = 0; e < 4; ++e) {
      base2[e] = b; meta[15+e] = b;
      b += (cnt[2+e] + 255) & ~255;
    }
    meta[19] = b;
  }
  __syncthreads();
  #pragma unroll
  for (int i = 0; i < 8; ++i) {
    int b = i * 1024 + tid;
    u64 lt = (1ull << lane) - 1ull;
    #pragma unroll
    for (int g = 0; g < 2; ++g) {
      u64 m = __ballot(myb0[i] == g);
      int pos = __popcll(m & lt);
      int wbase = 0;
      if (lane == 0 && m) wbase = atomicAdd(&cur[g], __popcll(m));
      wbase = __shfl(wbase, 0);
      if (myb0[i] == g) p1[base1[g] + wbase + pos] = b;
    }
    #pragma unroll
    for (int g = 0; g < 4; ++g) {
      u64 m = __ballot(myleaf[i] == g);
      int pos = __popcll(m & lt);
      int wbase = 0;
      if (lane == 0 && m) wbase = atomicAdd(&cur[2+g], __popcll(m));
      wbase = __shfl(wbase, 0);
      if (myleaf[i] == g) p2[base2[g] + wbase + pos] = b;
    }
  }
}

// x -> bf16 (copy if already bf16)
__global__ void k_cvtx(const void* __restrict__ x, u16* __restrict__ xb,
                       const int* __restrict__ meta) {
  int i = blockIdx.x * 256 + threadIdx.x;
  if (meta[20]) {
    ((uint4*)xb)[i] = ((const uint4*)x)[i];
  } else {
    const float4* p = (const float4*)x + (size_t)i * 2;
    float4 a = p[0], b = p[1];
    uint4 o;
    o.x = f2bf(a.x) | ((u32)f2bf(a.y) << 16);
    o.y = f2bf(a.z) | ((u32)f2bf(a.w) << 16);
    o.z = f2bf(b.x) | ((u32)f2bf(b.y) << 16);
    o.w = f2bf(b.z) | ((u32)f2bf(b.w) << 16);
    ((uint4*)xb)[i] = o;
  }
}

// transpose+convert weights into 7 slots of Wt[n][k] bf16.
__global__ void k_wt(const void* __restrict__ W0, const void* __restrict__ W1,
                     const void* __restrict__ W2, u16* __restrict__ wt,
                     const int* __restrict__ meta) {
  __shared__ u16 tile[64][66];
  int bid = blockIdx.x;
  int slot = bid >> 10;          // 1024 tiles per slot (32x32 of 64x64)
  int t = bid & 1023;
  int tr = t >> 5, tc = t & 31;
  const void* src; size_t eoff;
  if (slot == 0)      { src = W0; eoff = 0; }
  else if (slot <= 2) { src = W1; eoff = (size_t)(slot-1)*DD*DD; }
  else                { src = W2; eoff = (size_t)(slot-3)*DD*DD; }
  int r0 = tr*64, c0 = tc*64;
  int tid = threadIdx.x;
  int isbf = meta[20];
  #pragma unroll
  for (int i = 0; i < 4; ++i) {
    int idx = tid + i*256;
    int r = idx >> 4, c4 = (idx & 15) * 4;
    size_t goff = eoff + (size_t)(r0 + r)*DD + c0 + c4;
    u16 v0, v1, v2, v3;
    if (isbf) {
      ushort4 v = *(const ushort4*)((const u16*)src + goff);
      v0 = v.x; v1 = v.y; v2 = v.z; v3 = v.w;
    } else {
      float4 v = *(const float4*)((const float*)src + goff);
      v0 = f2bf(v.x); v1 = f2bf(v.y); v2 = f2bf(v.z); v3 = f2bf(v.w);
    }
    tile[r][c4+0] = v0; tile[r][c4+1] = v1;
    tile[r][c4+2] = v2; tile[r][c4+3] = v3;
  }
  __syncthreads();
  u16* dst = wt + (size_t)slot*DD*DD;
  #pragma unroll
  for (int i = 0; i < 2; ++i) {
    int idx = tid + i*256;          // 512 jobs: n = idx>>3, 16B chunk j = idx&7
    int n = idx >> 3, j = idx & 7;
    u16x8 o;
    #pragma unroll
    for (int k = 0; k < 8; ++k) o[k] = tile[j*8 + k][n];
    *(u16x8*)&dst[(size_t)(c0 + n)*DD + r0 + j*8] = o;
  }
}

// ---------------- GEMM: C = relu(A @ W + bias), expert-routed ----------------
// Pipelined phase schedule (T3+T4+T5+T1), RACE-FIXED ordering:
//   per tile t:  vmcnt(6)  [own tile-t loads drained]
//                s_barrier [publishes ALL waves' tile-t LDS writes]
//                stage t+3 || ds_read tile-t fragments
//                lgkmcnt(0); sched_barrier; setprio(1); 16x MFMA; setprio(0)
//                s_barrier [all reads of tile t retired before its buffer
//                           (t&3) is re-staged at iter t+1's stage of t+4]
//   vmcnt is per-wave: the drain MUST precede a barrier before any wave
//   reads LDS staged by other waves (round-1 bug: reads before barrier).
//   Ring of 4 K-tile buffers (A 16KB + B 8KB each = 96 KiB LDS);
//   steady-state vmcnt(6) = 2 tiles in flight, never 0 in main loop (T4);
//   tail peels 6 -> 3 -> 0.
#define SBA(T) ((u32)(((T) & 3) * 24576))
#define SBB(T) ((u32)(((T) & 3) * 24576 + 16384))

#define TILE(T, STAGE, VMN) do {                                             \
  asm volatile("s_waitcnt vmcnt(" #VMN ")" ::: "memory");                    \
  __builtin_amdgcn_s_barrier();                                              \
  {                                                                          \
    if (STAGE) {                                                             \
      const int t3 = (T) + 3;                                                \
      gld16(gA0 + (size_t)t3 * 32, sm + SBA(t3) + wid * 1024);               \
      gld16(gA1 + (size_t)t3 * 32, sm + SBA(t3) + 8192 + wid * 1024);        \
      gld16(gB0 + (size_t)t3 * 32, sm + SBB(t3) + wid * 1024);               \
    }                                                                        \
    const u32 sa = SBA(T) + aoff;                                            \
    const u32 sb = SBB(T) + boff;                                            \
    bf16x8 af[4], bfr[4];                                                    \
    _Pragma("unroll") for (int mt = 0; mt < 4; ++mt)                         \
      af[mt] = *(const bf16x8*)(sm + sa + mt * 1024);                        \
    _Pragma("unroll") for (int nt = 0; nt < 4; ++nt)                         \
      bfr[nt] = *(const bf16x8*)(sm + sb + nt * 1024);                       \
    asm volatile("s_waitcnt lgkmcnt(0)" ::: "memory");                       \
    __builtin_amdgcn_sched_barrier(0);                                       \
    __builtin_amdgcn_s_setprio(1);                                           \
    _Pragma("unroll") for (int mt = 0; mt < 4; ++mt)                         \
      _Pragma("unroll") for (int nt = 0; nt < 4; ++nt)                       \
        acc[mt][nt] = __builtin_amdgcn_mfma_f32_16x16x32_bf16(               \
            af[mt], bfr[nt], acc[mt][nt], 0, 0, 0);                          \
    __builtin_amdgcn_s_setprio(0);                                           \
    __builtin_amdgcn_s_barrier();                                            \
  }                                                                          \
} while (0)

__global__ __launch_bounds__(512, 2) void k_gemm(
    const u16* __restrict__ A, const u16* __restrict__ Wt,
    const void* __restrict__ bias, const int* __restrict__ perm,
    const int* __restrict__ bases, int nexp,
    void* __restrict__ Out, int final_out, const int* __restrict__ meta) {
  __shared__ __align__(16) char sm[4 * 24576];   // 96 KiB ring

  const int tid  = threadIdx.x;
  const int wid  = tid >> 6;
  const int lane = tid & 63;

  // T1: XCD-chunked bijective swizzle of the flattened grid (nwg % 8 == 0
  // for all three stages: 512 / 544 / 576). 16 consecutive swz share one
  // 256-row A panel -> per-XCD L2 A-locality.
  const u32 nwg = gridDim.x * gridDim.y;
  const u32 wg  = blockIdx.y * gridDim.x + blockIdx.x;
  const u32 cpx = nwg >> 3;
  const u32 swz = (wg & 7u) * cpx + (wg >> 3);
  const int m0 = (int)(swz >> 4) * 256;
  const int n0 = (int)(swz & 15u) * 128;

  int e = 0;
  if (nexp == 2)      e = (m0 >= bases[1]);
  else if (nexp == 4) e = (m0 >= bases[1]) + (m0 >= bases[2]) + (m0 >= bases[3]);
  if (perm && m0 >= bases[nexp]) return;   // fully-padded tail tile: nothing to do
  const u16* W = Wt + (size_t)e * DD * DD;

  // staging sources (per lane). One sweep = 512 thr x 16B = 8 KB = 128 rows
  // x 32k. Dest is linear (wave-uniform base + lane*16); source row/chunk
  // must match that linearization: row = wid*16 + lane/4, chunk = lane&3.
  const int sr = wid * 16 + (lane >> 2);
  const int kc = (lane & 3) * 8;
  int ar0 = m0 + sr, ar1 = m0 + 128 + sr;
  if (perm) {
    int v0 = perm[ar0]; ar0 = v0 < 0 ? 0 : v0;
    int v1 = perm[ar1]; ar1 = v1 < 0 ? 0 : v1;
  }
  const u16* gA0 = A + (size_t)ar0 * DD + kc;          // A rows   0..127 of tile
  const u16* gA1 = A + (size_t)ar1 * DD + kc;          // A rows 128..255
  const u16* gB0 = W + (size_t)(n0 + sr) * DD + kc;    // B rows   0..127

  // fragment read offsets (16x16x32 MFMA; layout identical to the verified
  // baseline: lane = q*16+cl reads row base+cl, k-chunk q*8).
  const int wm = wid >> 1, wn = wid & 1;
  const int q = lane >> 4, cl = lane & 15;
  const u32 aoff = (u32)((wm * 64 + cl) * 64 + q * 16);
  const u32 boff = (u32)((wn * 64 + cl) * 64 + q * 16);

  f32x4 zero = {0.0f, 0.0f, 0.0f, 0.0f};
  f32x4 acc[4][4];
  #pragma unroll
  for (int i = 0; i < 4; ++i)
    #pragma unroll
    for (int j = 0; j < 4; ++j) acc[i][j] = zero;

  // prologue: stage tiles 0,1,2 (tile-major issue order for vmcnt counting:
  // 3 loads per thread per tile).
  #pragma unroll
  for (int tt = 0; tt < 3; ++tt) {
    gld16(gA0 + (size_t)tt * 32, sm + SBA(tt) + wid * 1024);
    gld16(gA1 + (size_t)tt * 32, sm + SBA(tt) + 8192 + wid * 1024);
    gld16(gB0 + (size_t)tt * 32, sm + SBB(tt) + wid * 1024);
  }

  // main loop: 64 K-tiles. Steady state: at top of tile t, loads for tiles
  // t..t+2 (9 insts) outstanding -> vmcnt(6) drains tile t; stage tile t+3
  // after the publication barrier.
  #pragma unroll 1
  for (int t = 0; t < 61; ++t) TILE(t, true, 6);
  TILE(61, false, 6);
  TILE(62, false, 3);
  TILE(63, false, 0);

  // epilogue
  const int isbf = meta[20];
  float bv[4];
  #pragma unroll
  for (int nt = 0; nt < 4; ++nt) {
    int col = n0 + wn * 64 + nt * 16 + cl;
    bv[nt] = isbf ? bf2f(((const u16*)bias)[e * DD + col])
                  : ((const float*)bias)[e * DD + col];
  }
  #pragma unroll
  for (int mt = 0; mt < 4; ++mt) {
    int rbase = m0 + wm * 64 + mt * 16 + q * 4;
    #pragma unroll
    for (int r = 0; r < 4; ++r) {
      int row = rbase + r;
      int orow = row;
      if (perm) { orow = perm[row]; if (orow < 0) continue; }
      #pragma unroll
      for (int nt = 0; nt < 4; ++nt) {
        int col = n0 + wn * 64 + nt * 16 + cl;
        float v = acc[mt][nt][r] + bv[nt];
        v = v > 0.0f ? v : 0.0f;
        if (!final_out || isbf) ((u16*)Out)[(size_t)orow * DD + col] = f2bf(v);
        else                    ((float*)Out)[(size_t)orow * DD + col] = v;
      }
    }
  }
}

#undef TILE
#undef SBA
#undef SBB

extern "C" void kernel_launch(void* const* d_in, const int* in_sizes, int n_in,
                              void* d_out, int out_size, void* d_ws, size_t ws_size,
                              hipStream_t stream) {
  (void)in_sizes; (void)n_in; (void)out_size; (void)ws_size;
  const void* x  = d_in[0];
  const void* W0 = d_in[1];
  const void* b0 = d_in[2];
  const void* W1 = d_in[3];
  const void* b1 = d_in[4];
  const void* W2 = d_in[5];
  const void* b2 = d_in[6];
  const int*  pm = (const int*)d_in[7];

  char* ws  = (char*)d_ws;
  u16*  wt  = (u16*)(ws + OFF_WT);
  u16*  xb  = (u16*)(ws + OFF_XB);   // also reused as h1 after stage0
  u16*  h0  = (u16*)(ws + OFF_H0);
  u16*  h1  = xb;
  int*  p1  = (int*)(ws + OFF_P1);
  int*  p2  = (int*)(ws + OFF_P2);
  int*  meta= (int*)(ws + OFF_META);

  hipLaunchKernelGGL(k_detect, dim3(1),  dim3(256),  0, stream, (const u16*)x, meta);
  hipLaunchKernelGGL(k_route,  dim3(1),  dim3(1024), 0, stream, pm, p1, p2, meta);
  hipLaunchKernelGGL(k_cvtx,   dim3(BB*DD/8/256), dim3(256), 0, stream, x, xb, meta);
  hipLaunchKernelGGL(k_wt,     dim3(7*1024), dim3(256), 0, stream, W0, W1, W2, wt, meta);

  // stage 0: h0 = relu(x @ W0 + b0)            grid 16 n-tiles x 32 m-tiles
  hipLaunchKernelGGL(k_gemm, dim3(16, 32), dim3(512), 0, stream,
                     xb, wt, b0, (const int*)nullptr, (const int*)nullptr, 1,
                     (void*)h0, 0, meta);
  // stage 1: h1 = relu(h0 @ W1[bit0] + b1[bit0]), rows grouped by bit0
  hipLaunchKernelGGL(k_gemm, dim3(16, NP1/256), dim3(512), 0, stream,
                     h0, wt + (size_t)1*DD*DD, b1, p1, meta + 12, 2,
                     (void*)h1, 0, meta);
  // stage 2: y = relu(h1 @ W2[leaf] + b2[leaf]), rows grouped by leaf
  hipLaunchKernelGGL(k_gemm, dim3(16, NP2/256), dim3(512), 0, stream,
                     h1, wt + (size_t)3*DD*DD, b2, p2, meta + 15, 4,
                     d_out, 1, meta);
}

// Round 3
// 522.513 us; speedup vs baseline: 1.0683x; 1.0683x over previous
//
#include <hip/hip_runtime.h>

#define BB 8192
#define DD 2048
#define NSLOT 7
#define NP1 (BB + 2*256)   // 8704 (256-aligned groups)
#define NP2 (BB + 4*256)   // 9216

typedef unsigned short u16;
typedef unsigned int   u32;
typedef unsigned long long u64;

typedef __bf16 bf16x8 __attribute__((ext_vector_type(8)));
typedef float  f32x4  __attribute__((ext_vector_type(4)));
typedef u16    u16x8  __attribute__((ext_vector_type(8)));

// ---- workspace layout (bytes). h1 reuses the xb region (xb dead after stage0).
#define OFF_WT   0ull
#define OFF_XB   (OFF_WT + (size_t)NSLOT*DD*DD*2)    // 58,720,256
#define OFF_H0   (OFF_XB + (size_t)BB*DD*2)          // 92,274,688
#define OFF_P1   (OFF_H0 + (size_t)BB*DD*2)          // 125,829,120
#define OFF_P2   (OFF_P1 + (size_t)NP1*4)
#define OFF_META (OFF_P2 + (size_t)NP2*4)
// meta ints: [12..14] bases1, [15..19] bases2, [20] input-is-bf16 flag

__device__ __forceinline__ u16 f2bf(float f) {
  u32 u = __float_as_uint(f);
  u32 r = (u + 0x7FFFu + ((u >> 16) & 1u)) >> 16;
  return (u16)r;
}
__device__ __forceinline__ float bf2f(u16 u) {
  return __uint_as_float(((u32)u) << 16);
}

__device__ __forceinline__ void gld16(const void* g, void* l) {
  __builtin_amdgcn_global_load_lds(
      (const __attribute__((address_space(1))) void*)g,
      (__attribute__((address_space(3))) void*)l, 16, 0, 0);
}

// ---------------- setup kernels ----------------

// Decide whether buffers are bf16-stored or fp32-stored.
__global__ void k_detect(const u16* x, int* meta) {
  __shared__ int cnt, cntz;
  if (threadIdx.x == 0) { cnt = 0; cntz = 0; }
  __syncthreads();
  u16 u = x[threadIdx.x * 17];       // odd stride mixes both parities
  int ex = (u >> 7) & 0xFF;
  int sane = (ex == 0) || (ex >= 112 && ex <= 143);
  atomicAdd(&cnt, sane);
  atomicAdd(&cntz, (u == 0) ? 1 : 0);
  __syncthreads();
  if (threadIdx.x == 0) meta[20] = (cnt >= 205 && cntz < 64) ? 1 : 0;
}

// Single-block routing: count via wave ballots, 256-align group bases,
// fill perms with ballot-prefix slot assignment.
__global__ __launch_bounds__(1024) void k_route(const int* __restrict__ pm,
                                                int* __restrict__ p1,
                                                int* __restrict__ p2,
                                                int* __restrict__ meta) {
  __shared__ int cnt[6];            // [0..1] stage1, [2..5] stage2
  __shared__ int cur[6];
  __shared__ int base1[2], base2[4];
  const int tid = threadIdx.x;
  const int lane = tid & 63;
  if (tid < 6) { cnt[tid] = 0; cur[tid] = 0; }
  __syncthreads();

  for (int i = tid; i < NP1; i += 1024) p1[i] = -1;
  for (int i = tid; i < NP2; i += 1024) p2[i] = -1;

  int myb0[8], myleaf[8];
  #pragma unroll
  for (int i = 0; i < 8; ++i) {
    int b = i * 1024 + tid;
    int b0 = pm[b*3] & 1, b1 = pm[b*3+1] & 1;
    myb0[i] = b0; myleaf[i] = b0*2 + b1;
  }
  #pragma unroll
  for (int i = 0; i < 8; ++i) {
    u64 m0 = __ballot(myb0[i] == 0);
    if (lane == 0) {
      atomicAdd(&cnt[0], __popcll(m0));
      atomicAdd(&cnt[1], 64 - __popcll(m0));
    }
    #pragma unroll
    for (int e = 0; e < 4; ++e) {
      u64 me = __ballot(myleaf[i] == e);
      if (lane == 0) atomicAdd(&cnt[2+e], __popcll(me));
    }
  }
  __syncthreads();
  if (tid == 0) {
    base1[0] = 0;
    base1[1] = (cnt[0] + 255) & ~255;
    meta[12] = 0; meta[13] = base1[1];
    meta[14] = base1[1] + ((cnt[1] + 255) & ~255);
    int b = 0;
    #pragma unroll
    for (int e = 0; e < 4; ++e) {
      base2[e] = b; meta[15+e] = b;
      b += (cnt[2+e] + 255) & ~255;
    }
    meta[19] = b;
  }
  __syncthreads();
  #pragma unroll
  for (int i = 0; i < 8; ++i) {
    int b = i * 1024 + tid;
    u64 lt = (1ull << lane) - 1ull;
    #pragma unroll
    for (int g = 0; g < 2; ++g) {
      u64 m = __ballot(myb0[i] == g);
      int pos = __popcll(m & lt);
      int wbase = 0;
      if (lane == 0 && m) wbase = atomicAdd(&cur[g], __popcll(m));
      wbase = __shfl(wbase, 0);
      if (myb0[i] == g) p1[base1[g] + wbase + pos] = b;
    }
    #pragma unroll
    for (int g = 0; g < 4; ++g) {
      u64 m = __ballot(myleaf[i] == g);
      int pos = __popcll(m & lt);
      int wbase = 0;
      if (lane == 0 && m) wbase = atomicAdd(&cur[2+g], __popcll(m));
      wbase = __shfl(wbase, 0);
      if (myleaf[i] == g) p2[base2[g] + wbase + pos] = b;
    }
  }
}

// x -> bf16 (copy if already bf16)
__global__ void k_cvtx(const void* __restrict__ x, u16* __restrict__ xb,
                       const int* __restrict__ meta) {
  int i = blockIdx.x * 256 + threadIdx.x;
  if (meta[20]) {
    ((uint4*)xb)[i] = ((const uint4*)x)[i];
  } else {
    const float4* p = (const float4*)x + (size_t)i * 2;
    float4 a = p[0], b = p[1];
    uint4 o;
    o.x = f2bf(a.x) | ((u32)f2bf(a.y) << 16);
    o.y = f2bf(a.z) | ((u32)f2bf(a.w) << 16);
    o.z = f2bf(b.x) | ((u32)f2bf(b.y) << 16);
    o.w = f2bf(b.z) | ((u32)f2bf(b.w) << 16);
    ((uint4*)xb)[i] = o;
  }
}

// transpose+convert weights into 7 slots of Wt[n][k] bf16.
__global__ void k_wt(const void* __restrict__ W0, const void* __restrict__ W1,
                     const void* __restrict__ W2, u16* __restrict__ wt,
                     const int* __restrict__ meta) {
  __shared__ u16 tile[64][66];
  int bid = blockIdx.x;
  int slot = bid >> 10;          // 1024 tiles per slot (32x32 of 64x64)
  int t = bid & 1023;
  int tr = t >> 5, tc = t & 31;
  const void* src; size_t eoff;
  if (slot == 0)      { src = W0; eoff = 0; }
  else if (slot <= 2) { src = W1; eoff = (size_t)(slot-1)*DD*DD; }
  else                { src = W2; eoff = (size_t)(slot-3)*DD*DD; }
  int r0 = tr*64, c0 = tc*64;
  int tid = threadIdx.x;
  int isbf = meta[20];
  #pragma unroll
  for (int i = 0; i < 4; ++i) {
    int idx = tid + i*256;
    int r = idx >> 4, c4 = (idx & 15) * 4;
    size_t goff = eoff + (size_t)(r0 + r)*DD + c0 + c4;
    u16 v0, v1, v2, v3;
    if (isbf) {
      ushort4 v = *(const ushort4*)((const u16*)src + goff);
      v0 = v.x; v1 = v.y; v2 = v.z; v3 = v.w;
    } else {
      float4 v = *(const float4*)((const float*)src + goff);
      v0 = f2bf(v.x); v1 = f2bf(v.y); v2 = f2bf(v.z); v3 = f2bf(v.w);
    }
    tile[r][c4+0] = v0; tile[r][c4+1] = v1;
    tile[r][c4+2] = v2; tile[r][c4+3] = v3;
  }
  __syncthreads();
  u16* dst = wt + (size_t)slot*DD*DD;
  #pragma unroll
  for (int i = 0; i < 2; ++i) {
    int idx = tid + i*256;          // 512 jobs: n = idx>>3, 16B chunk j = idx&7
    int n = idx >> 3, j = idx & 7;
    u16x8 o;
    #pragma unroll
    for (int k = 0; k < 8; ++k) o[k] = tile[j*8 + k][n];
    *(u16x8*)&dst[(size_t)(c0 + n)*DD + r0 + j*8] = o;
  }
}

// ---------------- GEMM: C = relu(A @ W + bias), expert-routed ----------------
// BM=256 x BN=128, BK=32, 256 threads = 4 waves (2M x 2N), per-wave 128x64
// (acc[8][4]) -> 32 MFMA per 12 ds_read_b128 per wave (1.33x the reuse of the
// round-2 64x64 wave, which was LDS-read capped at ~60% clean).
// XOR chunk swizzle RESTORED (round-2 regression: 8-way bank conflict, 8.65M):
//   logical 16B chunk c of LDS row r lives at physical chunk c ^ ((r>>1)&3).
//   Store side: global_load_lds dest stays linear; per-lane GLOBAL source
//   k-chunk pre-swizzled (kk). Read side: sw = q ^ ((cl>>1)&3) -> 2-way (free).
// Ring of 3 K-tile buffers (A 16KB + B 8KB = 24KB each, 72KB LDS) ->
// 2 blocks/CU (8 waves/CU). Stage distance 2; per tile t:
//   vmcnt(6) [own t loads drained] -> s_barrier [publish all waves' writes]
//   -> stage t+2 || ds_read t frags -> lgkmcnt(0); sched_barrier;
//   setprio(1); 32x MFMA; setprio(0) -> s_barrier.
// Steady vmcnt(6) = 1 full tile in flight, never 0 in main loop; tail 6->0.
#define STG(SBUF, TI) do {                                                   \
    const size_t ko = (size_t)(TI) * 32;                                     \
    gld16(gA0 + ko, sm + (SBUF)*24576 +         0 + widoff);                 \
    gld16(gA1 + ko, sm + (SBUF)*24576 +      4096 + widoff);                 \
    gld16(gA2 + ko, sm + (SBUF)*24576 +      8192 + widoff);                 \
    gld16(gA3 + ko, sm + (SBUF)*24576 +     12288 + widoff);                 \
    gld16(gB0 + ko, sm + (SBUF)*24576 + 16384 + 0 + widoff);                 \
    gld16(gB1 + ko, sm + (SBUF)*24576 + 16384 + 4096 + widoff);              \
  } while (0)

#define TILE(BUF, T, STAGE, SBUF, VMN) do {                                  \
  asm volatile("s_waitcnt vmcnt(" #VMN ")" ::: "memory");                    \
  __builtin_amdgcn_s_barrier();                                              \
  {                                                                          \
    if (STAGE) STG(SBUF, (T) + 2);                                           \
    const u32 sa = (BUF)*24576 + aoff;                                       \
    const u32 sb = (BUF)*24576 + 16384 + boff;                               \
    bf16x8 af[8], bfr[4];                                                    \
    _Pragma("unroll") for (int mt = 0; mt < 8; ++mt)                         \
      af[mt] = *(const bf16x8*)(sm + sa + mt * 1024);                        \
    _Pragma("unroll") for (int nt = 0; nt < 4; ++nt)                         \
      bfr[nt] = *(const bf16x8*)(sm + sb + nt * 1024);                       \
    asm volatile("s_waitcnt lgkmcnt(0)" ::: "memory");                       \
    __builtin_amdgcn_sched_barrier(0);                                       \
    __builtin_amdgcn_s_setprio(1);                                           \
    _Pragma("unroll") for (int mt = 0; mt < 8; ++mt)                         \
      _Pragma("unroll") for (int nt = 0; nt < 4; ++nt)                       \
        acc[mt][nt] = __builtin_amdgcn_mfma_f32_16x16x32_bf16(               \
            af[mt], bfr[nt], acc[mt][nt], 0, 0, 0);                          \
    __builtin_amdgcn_s_setprio(0);                                           \
    __builtin_amdgcn_s_barrier();                                            \
  }                                                                          \
} while (0)

__global__ __launch_bounds__(256, 2) void k_gemm(
    const u16* __restrict__ A, const u16* __restrict__ Wt,
    const void* __restrict__ bias, const int* __restrict__ perm,
    const int* __restrict__ bases, int nexp,
    void* __restrict__ Out, int final_out, const int* __restrict__ meta) {
  __shared__ __align__(16) char sm[3 * 24576];   // 72 KiB ring

  const int tid  = threadIdx.x;
  const int wid  = tid >> 6;
  const int lane = tid & 63;
  const u32 widoff = (u32)wid * 1024;

  // T1: XCD-chunked bijective swizzle (nwg % 8 == 0 for 512/544/576).
  // Each XCD gets a contiguous m-range -> A-panel L2 locality.
  const u32 nwg = gridDim.x * gridDim.y;
  const u32 wg  = blockIdx.y * gridDim.x + blockIdx.x;
  const u32 cpx = nwg >> 3;
  const u32 swz = (wg & 7u) * cpx + (wg >> 3);
  const int m0 = (int)(swz >> 4) * 256;
  const int n0 = (int)(swz & 15u) * 128;

  int e = 0;
  if (nexp == 2)      e = (m0 >= bases[1]);
  else if (nexp == 4) e = (m0 >= bases[1]) + (m0 >= bases[2]) + (m0 >= bases[3]);
  if (perm && m0 >= bases[nexp]) return;   // fully-padded tail tile
  const u16* W = Wt + (size_t)e * DD * DD;

  // staging sources. Per tile: 6 jobs x (256 thr x 16B) = 24KB.
  // Job j dest byte = j*4096 + tid*16 -> LDS row = j*64 + (tid>>2), phys
  // chunk = tid&3. Source must hold logical chunk (tid&3) ^ sel(row);
  // sel(row) = (row>>1)&3 = (tid>>3)&3 (j*64 rows -> j*32 = 0 mod 4).
  const int sr = tid >> 2;
  const int kc = ((tid & 3) ^ ((tid >> 3) & 3)) * 8;   // pre-swizzled source k
  int ar[4];
  #pragma unroll
  for (int j = 0; j < 4; ++j) {
    int r = m0 + j * 64 + sr;
    if (perm) { int v = perm[r]; r = (v < 0) ? 0 : v; }
    ar[j] = r;
  }
  const u16* gA0 = A + (size_t)ar[0] * DD + kc;
  const u16* gA1 = A + (size_t)ar[1] * DD + kc;
  const u16* gA2 = A + (size_t)ar[2] * DD + kc;
  const u16* gA3 = A + (size_t)ar[3] * DD + kc;
  const u16* gB0 = W + (size_t)(n0 + sr) * DD + kc;
  const u16* gB1 = W + (size_t)(n0 + 64 + sr) * DD + kc;

  // fragment read offsets. Wave: wm = wid>>1 (M half, 128 rows),
  // wn = wid&1 (N half, 64 cols). Lane q = lane>>4, cl = lane&15.
  // Row R = base + cl; sel(R) = (cl>>1)&3 (base = 0 mod 16);
  // physical chunk of logical chunk q: sw = q ^ ((cl>>1)&3) -> 2-way free.
  const int wm = wid >> 1, wn = wid & 1;
  const int q = lane >> 4, cl = lane & 15;
  const int sw = q ^ ((cl >> 1) & 3);
  const u32 aoff = (u32)((wm * 128 + cl) * 64 + sw * 16);
  const u32 boff = (u32)((wn * 64 + cl) * 64 + sw * 16);

  f32x4 zero = {0.0f, 0.0f, 0.0f, 0.0f};
  f32x4 acc[8][4];
  #pragma unroll
  for (int i = 0; i < 8; ++i)
    #pragma unroll
    for (int j = 0; j < 4; ++j) acc[i][j] = zero;

  // prologue: stage tiles 0,1 (12 loads outstanding).
  STG(0, 0);
  STG(1, 1);

  // main loop: 64 K-tiles, ring phase = tile % 3 (compile-time via 3x body).
  #pragma unroll 1
  for (int t = 0; t < 60; t += 3) {
    TILE(0, t + 0, 1, 2, 6);
    TILE(1, t + 1, 1, 0, 6);
    TILE(2, t + 2, 1, 1, 6);
  }
  TILE(0, 60, 1, 2, 6);
  TILE(1, 61, 1, 0, 6);
  TILE(2, 62, 0, 0, 6);
  TILE(0, 63, 0, 0, 0);

  // epilogue
  const int isbf = meta[20];
  float bv[4];
  #pragma unroll
  for (int nt = 0; nt < 4; ++nt) {
    int col = n0 + wn * 64 + nt * 16 + cl;
    bv[nt] = isbf ? bf2f(((const u16*)bias)[e * DD + col])
                  : ((const float*)bias)[e * DD + col];
  }
  #pragma unroll
  for (int mt = 0; mt < 8; ++mt) {
    int rbase = m0 + wm * 128 + mt * 16 + q * 4;
    #pragma unroll
    for (int r = 0; r < 4; ++r) {
      int row = rbase + r;
      int orow = row;
      if (perm) { orow = perm[row]; if (orow < 0) continue; }
      #pragma unroll
      for (int nt = 0; nt < 4; ++nt) {
        int col = n0 + wn * 64 + nt * 16 + cl;
        float v = acc[mt][nt][r] + bv[nt];
        v = v > 0.0f ? v : 0.0f;
        if (!final_out || isbf) ((u16*)Out)[(size_t)orow * DD + col] = f2bf(v);
        else                    ((float*)Out)[(size_t)orow * DD + col] = v;
      }
    }
  }
}

#undef TILE
#undef STG

extern "C" void kernel_launch(void* const* d_in, const int* in_sizes, int n_in,
                              void* d_out, int out_size, void* d_ws, size_t ws_size,
                              hipStream_t stream) {
  (void)in_sizes; (void)n_in; (void)out_size; (void)ws_size;
  const void* x  = d_in[0];
  const void* W0 = d_in[1];
  const void* b0 = d_in[2];
  const void* W1 = d_in[3];
  const void* b1 = d_in[4];
  const void* W2 = d_in[5];
  const void* b2 = d_in[6];
  const int*  pm = (const int*)d_in[7];

  char* ws  = (char*)d_ws;
  u16*  wt  = (u16*)(ws + OFF_WT);
  u16*  xb  = (u16*)(ws + OFF_XB);   // also reused as h1 after stage0
  u16*  h0  = (u16*)(ws + OFF_H0);
  u16*  h1  = xb;
  int*  p1  = (int*)(ws + OFF_P1);
  int*  p2  = (int*)(ws + OFF_P2);
  int*  meta= (int*)(ws + OFF_META);

  hipLaunchKernelGGL(k_detect, dim3(1),  dim3(256),  0, stream, (const u16*)x, meta);
  hipLaunchKernelGGL(k_route,  dim3(1),  dim3(1024), 0, stream, pm, p1, p2, meta);
  hipLaunchKernelGGL(k_cvtx,   dim3(BB*DD/8/256), dim3(256), 0, stream, x, xb, meta);
  hipLaunchKernelGGL(k_wt,     dim3(7*1024), dim3(256), 0, stream, W0, W1, W2, wt, meta);

  // stage 0: h0 = relu(x @ W0 + b0)            grid 16 n-tiles x 32 m-tiles
  hipLaunchKernelGGL(k_gemm, dim3(16, 32), dim3(256), 0, stream,
                     xb, wt, b0, (const int*)nullptr, (const int*)nullptr, 1,
                     (void*)h0, 0, meta);
  // stage 1: h1 = relu(h0 @ W1[bit0] + b1[bit0]), rows grouped by bit0
  hipLaunchKernelGGL(k_gemm, dim3(16, NP1/256), dim3(256), 0, stream,
                     h0, wt + (size_t)1*DD*DD, b1, p1, meta + 12, 2,
                     (void*)h1, 0, meta);
  // stage 2: y = relu(h1 @ W2[leaf] + b2[leaf]), rows grouped by leaf
  hipLaunchKernelGGL(k_gemm, dim3(16, NP2/256), dim3(256), 0, stream,
                     h1, wt + (size_t)3*DD*DD, b2, p2, meta + 15, 4,
                     d_out, 1, meta);
}

// Round 4
// 500.075 us; speedup vs baseline: 1.1162x; 1.0449x over previous
//
#include <hip/hip_runtime.h>

#define BB 8192
#define DD 2048
#define NSLOT 7
#define NP1 (BB + 2*256)   // 8704 (256-aligned groups)
#define NP2 (BB + 4*256)   // 9216

typedef unsigned short u16;
typedef unsigned int   u32;
typedef unsigned long long u64;

typedef __bf16 bf16x8 __attribute__((ext_vector_type(8)));
typedef float  f32x4  __attribute__((ext_vector_type(4)));
typedef u16    u16x8  __attribute__((ext_vector_type(8)));

// ---- workspace layout (bytes). h1 reuses the xb region (xb dead after stage0).
#define OFF_WT   0ull
#define OFF_XB   (OFF_WT + (size_t)NSLOT*DD*DD*2)    // 58,720,256
#define OFF_H0   (OFF_XB + (size_t)BB*DD*2)          // 92,274,688
#define OFF_P1   (OFF_H0 + (size_t)BB*DD*2)          // 125,829,120
#define OFF_P2   (OFF_P1 + (size_t)NP1*4)
#define OFF_META (OFF_P2 + (size_t)NP2*4)
// meta ints: [12..14] bases1, [15..19] bases2, [20] input-is-bf16 flag

__device__ __forceinline__ u16 f2bf(float f) {
  u32 u = __float_as_uint(f);
  u32 r = (u + 0x7FFFu + ((u >> 16) & 1u)) >> 16;
  return (u16)r;
}
__device__ __forceinline__ float bf2f(u16 u) {
  return __uint_as_float(((u32)u) << 16);
}

__device__ __forceinline__ void gld16(const void* g, void* l) {
  __builtin_amdgcn_global_load_lds(
      (const __attribute__((address_space(1))) void*)g,
      (__attribute__((address_space(3))) void*)l, 16, 0, 0);
}

// ---------------- setup kernels ----------------

// Decide whether buffers are bf16-stored or fp32-stored.
__global__ void k_detect(const u16* x, int* meta) {
  __shared__ int cnt, cntz;
  if (threadIdx.x == 0) { cnt = 0; cntz = 0; }
  __syncthreads();
  u16 u = x[threadIdx.x * 17];       // odd stride mixes both parities
  int ex = (u >> 7) & 0xFF;
  int sane = (ex == 0) || (ex >= 112 && ex <= 143);
  atomicAdd(&cnt, sane);
  atomicAdd(&cntz, (u == 0) ? 1 : 0);
  __syncthreads();
  if (threadIdx.x == 0) meta[20] = (cnt >= 205 && cntz < 64) ? 1 : 0;
}

// Single-block routing: count via wave ballots, 256-align group bases,
// fill perms with ballot-prefix slot assignment.
__global__ __launch_bounds__(1024) void k_route(const int* __restrict__ pm,
                                                int* __restrict__ p1,
                                                int* __restrict__ p2,
                                                int* __restrict__ meta) {
  __shared__ int cnt[6];            // [0..1] stage1, [2..5] stage2
  __shared__ int cur[6];
  __shared__ int base1[2], base2[4];
  const int tid = threadIdx.x;
  const int lane = tid & 63;
  if (tid < 6) { cnt[tid] = 0; cur[tid] = 0; }
  __syncthreads();

  for (int i = tid; i < NP1; i += 1024) p1[i] = -1;
  for (int i = tid; i < NP2; i += 1024) p2[i] = -1;

  int myb0[8], myleaf[8];
  #pragma unroll
  for (int i = 0; i < 8; ++i) {
    int b = i * 1024 + tid;
    int b0 = pm[b*3] & 1, b1 = pm[b*3+1] & 1;
    myb0[i] = b0; myleaf[i] = b0*2 + b1;
  }
  #pragma unroll
  for (int i = 0; i < 8; ++i) {
    u64 m0 = __ballot(myb0[i] == 0);
    if (lane == 0) {
      atomicAdd(&cnt[0], __popcll(m0));
      atomicAdd(&cnt[1], 64 - __popcll(m0));
    }
    #pragma unroll
    for (int e = 0; e < 4; ++e) {
      u64 me = __ballot(myleaf[i] == e);
      if (lane == 0) atomicAdd(&cnt[2+e], __popcll(me));
    }
  }
  __syncthreads();
  if (tid == 0) {
    base1[0] = 0;
    base1[1] = (cnt[0] + 255) & ~255;
    meta[12] = 0; meta[13] = base1[1];
    meta[14] = base1[1] + ((cnt[1] + 255) & ~255);
    int b = 0;
    #pragma unroll
    for (int e = 0; e < 4; ++e) {
      base2[e] = b; meta[15+e] = b;
      b += (cnt[2+e] + 255) & ~255;
    }
    meta[19] = b;
  }
  __syncthreads();
  #pragma unroll
  for (int i = 0; i < 8; ++i) {
    int b = i * 1024 + tid;
    u64 lt = (1ull << lane) - 1ull;
    #pragma unroll
    for (int g = 0; g < 2; ++g) {
      u64 m = __ballot(myb0[i] == g);
      int pos = __popcll(m & lt);
      int wbase = 0;
      if (lane == 0 && m) wbase = atomicAdd(&cur[g], __popcll(m));
      wbase = __shfl(wbase, 0);
      if (myb0[i] == g) p1[base1[g] + wbase + pos] = b;
    }
    #pragma unroll
    for (int g = 0; g < 4; ++g) {
      u64 m = __ballot(myleaf[i] == g);
      int pos = __popcll(m & lt);
      int wbase = 0;
      if (lane == 0 && m) wbase = atomicAdd(&cur[2+g], __popcll(m));
      wbase = __shfl(wbase, 0);
      if (myleaf[i] == g) p2[base2[g] + wbase + pos] = b;
    }
  }
}

// x -> bf16 (copy if already bf16)
__global__ void k_cvtx(const void* __restrict__ x, u16* __restrict__ xb,
                       const int* __restrict__ meta) {
  int i = blockIdx.x * 256 + threadIdx.x;
  if (meta[20]) {
    ((uint4*)xb)[i] = ((const uint4*)x)[i];
  } else {
    const float4* p = (const float4*)x + (size_t)i * 2;
    float4 a = p[0], b = p[1];
    uint4 o;
    o.x = f2bf(a.x) | ((u32)f2bf(a.y) << 16);
    o.y = f2bf(a.z) | ((u32)f2bf(a.w) << 16);
    o.z = f2bf(b.x) | ((u32)f2bf(b.y) << 16);
    o.w = f2bf(b.z) | ((u32)f2bf(b.w) << 16);
    ((uint4*)xb)[i] = o;
  }
}

// transpose+convert weights into 7 slots of Wt[n][k] bf16.
__global__ void k_wt(const void* __restrict__ W0, const void* __restrict__ W1,
                     const void* __restrict__ W2, u16* __restrict__ wt,
                     const int* __restrict__ meta) {
  __shared__ u16 tile[64][66];
  int bid = blockIdx.x;
  int slot = bid >> 10;          // 1024 tiles per slot (32x32 of 64x64)
  int t = bid & 1023;
  int tr = t >> 5, tc = t & 31;
  const void* src; size_t eoff;
  if (slot == 0)      { src = W0; eoff = 0; }
  else if (slot <= 2) { src = W1; eoff = (size_t)(slot-1)*DD*DD; }
  else                { src = W2; eoff = (size_t)(slot-3)*DD*DD; }
  int r0 = tr*64, c0 = tc*64;
  int tid = threadIdx.x;
  int isbf = meta[20];
  #pragma unroll
  for (int i = 0; i < 4; ++i) {
    int idx = tid + i*256;
    int r = idx >> 4, c4 = (idx & 15) * 4;
    size_t goff = eoff + (size_t)(r0 + r)*DD + c0 + c4;
    u16 v0, v1, v2, v3;
    if (isbf) {
      ushort4 v = *(const ushort4*)((const u16*)src + goff);
      v0 = v.x; v1 = v.y; v2 = v.z; v3 = v.w;
    } else {
      float4 v = *(const float4*)((const float*)src + goff);
      v0 = f2bf(v.x); v1 = f2bf(v.y); v2 = f2bf(v.z); v3 = f2bf(v.w);
    }
    tile[r][c4+0] = v0; tile[r][c4+1] = v1;
    tile[r][c4+2] = v2; tile[r][c4+3] = v3;
  }
  __syncthreads();
  u16* dst = wt + (size_t)slot*DD*DD;
  #pragma unroll
  for (int i = 0; i < 2; ++i) {
    int idx = tid + i*256;          // 512 jobs: n = idx>>3, 16B chunk j = idx&7
    int n = idx >> 3, j = idx & 7;
    u16x8 o;
    #pragma unroll
    for (int k = 0; k < 8; ++k) o[k] = tile[j*8 + k][n];
    *(u16x8*)&dst[(size_t)(c0 + n)*DD + r0 + j*8] = o;
  }
}

// ---------------- GEMM: C = relu(A @ W + bias), expert-routed ----------------
// BM=256 x BN=128, BK=32, 512 threads = 8 waves (4M x 2N), per-wave 64x64
// (acc[4][4]) -> 16-MFMA phase clusters (m201 granularity) with 8 ds_read +
// 3 gld each. 2 blocks/CU (72KB LDS, VGPR<=128 via launch_bounds) -> 4
// waves/SIMD from 2 INDEPENDENT blocks at different K-tiles: fills the
// lgkmcnt/barrier stalls that capped round-3 (2 waves/SIMD) at MfmaUtil 25%.
// XOR chunk swizzle (verified 0 conflicts): logical 16B chunk c of LDS row r
// at physical chunk c ^ ((r>>1)&3); linear gld dest + pre-swizzled global
// source k-chunk; read side sw = q ^ ((cl>>1)&3).
// Ring of 3 K-tile buffers (A 16KB + B 8KB = 24KB each). Stage distance 2.
// Per tile t: vmcnt(3) [own t loads drained, t+1 stays in flight — never 0]
//   -> s_barrier [publish all waves' t writes]
//   -> stage t+2 (3 gld) || ds_read t (8x b128)
//   -> lgkmcnt(0); sched_barrier; setprio(1); 16 MFMA; setprio(0)
//   -> s_barrier [t's readers done before buf reuse]. Tail: vmcnt 3 -> 0.
#define STG(SBUF, TI) do {                                                   \
    const size_t ko = (size_t)(TI) * 32;                                     \
    gld16(gA0 + ko, sm + (SBUF)*24576 +         0 + widoff);                 \
    gld16(gA1 + ko, sm + (SBUF)*24576 +      8192 + widoff);                 \
    gld16(gB0 + ko, sm + (SBUF)*24576 +     16384 + widoff);                 \
  } while (0)

#define TILE(BUF, T, STAGE, SBUF, VMN) do {                                  \
  asm volatile("s_waitcnt vmcnt(" #VMN ")" ::: "memory");                    \
  __builtin_amdgcn_s_barrier();                                              \
  {                                                                          \
    if (STAGE) STG(SBUF, (T) + 2);                                           \
    const u32 sa = (BUF)*24576 + aoff;                                       \
    const u32 sb = (BUF)*24576 + 16384 + boff;                               \
    bf16x8 af[4], bfr[4];                                                    \
    _Pragma("unroll") for (int mt = 0; mt < 4; ++mt)                         \
      af[mt] = *(const bf16x8*)(sm + sa + mt * 1024);                        \
    _Pragma("unroll") for (int nt = 0; nt < 4; ++nt)                         \
      bfr[nt] = *(const bf16x8*)(sm + sb + nt * 1024);                       \
    asm volatile("s_waitcnt lgkmcnt(0)" ::: "memory");                       \
    __builtin_amdgcn_sched_barrier(0);                                       \
    __builtin_amdgcn_s_setprio(1);                                           \
    _Pragma("unroll") for (int mt = 0; mt < 4; ++mt)                         \
      _Pragma("unroll") for (int nt = 0; nt < 4; ++nt)                       \
        acc[mt][nt] = __builtin_amdgcn_mfma_f32_16x16x32_bf16(               \
            af[mt], bfr[nt], acc[mt][nt], 0, 0, 0);                          \
    __builtin_amdgcn_s_setprio(0);                                           \
    __builtin_amdgcn_s_barrier();                                            \
  }                                                                          \
} while (0)

__global__ __launch_bounds__(512, 4) void k_gemm(
    const u16* __restrict__ A, const u16* __restrict__ Wt,
    const void* __restrict__ bias, const int* __restrict__ perm,
    const int* __restrict__ bases, int nexp,
    void* __restrict__ Out, int final_out, const int* __restrict__ meta) {
  __shared__ __align__(16) char sm[3 * 24576];   // 72 KiB ring -> 2 blocks/CU

  const int tid  = threadIdx.x;
  const int wid  = tid >> 6;
  const int lane = tid & 63;
  const u32 widoff = (u32)wid * 1024;

  // T1: XCD-chunked bijective swizzle (nwg % 8 == 0 for 512/544/576).
  const u32 nwg = gridDim.x * gridDim.y;
  const u32 wg  = blockIdx.y * gridDim.x + blockIdx.x;
  const u32 cpx = nwg >> 3;
  const u32 swz = (wg & 7u) * cpx + (wg >> 3);
  const int m0 = (int)(swz >> 4) * 256;
  const int n0 = (int)(swz & 15u) * 128;

  int e = 0;
  if (nexp == 2)      e = (m0 >= bases[1]);
  else if (nexp == 4) e = (m0 >= bases[1]) + (m0 >= bases[2]) + (m0 >= bases[3]);
  if (perm && m0 >= bases[nexp]) return;   // fully-padded tail tile
  const u16* W = Wt + (size_t)e * DD * DD;

  // staging sources. 3 gld/thread/tile, each sweep = 512 thr x 16B = 8KB =
  // 128 rows x 64B. Dest row = wid*16 + lane/4 == tid>>2; phys chunk = tid&3.
  // Source logical chunk = (tid&3) ^ ((row>>1)&3) = (tid&3) ^ ((tid>>3)&3).
  const int sr = tid >> 2;
  const int kc = ((tid & 3) ^ ((tid >> 3) & 3)) * 8;   // pre-swizzled source k
  int ar0i = m0 + sr, ar1i = m0 + 128 + sr;
  if (perm) {
    int v0 = perm[ar0i]; ar0i = (v0 < 0) ? 0 : v0;
    int v1 = perm[ar1i]; ar1i = (v1 < 0) ? 0 : v1;
  }
  const u16* gA0 = A + (size_t)ar0i * DD + kc;         // A rows   0..127
  const u16* gA1 = A + (size_t)ar1i * DD + kc;         // A rows 128..255
  const u16* gB0 = W + (size_t)(n0 + sr) * DD + kc;    // B rows   0..127

  // fragment read offsets. 8 waves: wm = wid>>1 (0..3), wn = wid&1 (0..1).
  // Per-wave 64x64: rows wm*64 + mt*16 + cl, cols wn*64 + nt*16.
  // Read swizzle sw = q ^ ((cl>>1)&3) -> exact 2-way (free).
  const int wm = wid >> 1, wn = wid & 1;
  const int q = lane >> 4, cl = lane & 15;
  const int sw = q ^ ((cl >> 1) & 3);
  const u32 aoff = (u32)((wm * 64 + cl) * 64 + sw * 16);
  const u32 boff = (u32)((wn * 64 + cl) * 64 + sw * 16);

  f32x4 zero = {0.0f, 0.0f, 0.0f, 0.0f};
  f32x4 acc[4][4];
  #pragma unroll
  for (int i = 0; i < 4; ++i)
    #pragma unroll
    for (int j = 0; j < 4; ++j) acc[i][j] = zero;

  // prologue: stage tiles 0,1 (6 gld outstanding per wave).
  STG(0, 0);
  STG(1, 1);

  // main loop: 64 K-tiles, ring = tile % 3 (compile-time via 3x body).
  // Steady: at tile-t top, outstanding = t(3) + t+1(3); vmcnt(3) drains t.
  #pragma unroll 1
  for (int t = 0; t < 60; t += 3) {
    TILE(0, t + 0, 1, 2, 3);
    TILE(1, t + 1, 1, 0, 3);
    TILE(2, t + 2, 1, 1, 3);
  }
  TILE(0, 60, 1, 2, 3);
  TILE(1, 61, 1, 0, 3);
  TILE(2, 62, 0, 0, 3);
  TILE(0, 63, 0, 0, 0);

  // epilogue
  const int isbf = meta[20];
  float bv[4];
  #pragma unroll
  for (int nt = 0; nt < 4; ++nt) {
    int col = n0 + wn * 64 + nt * 16 + cl;
    bv[nt] = isbf ? bf2f(((const u16*)bias)[e * DD + col])
                  : ((const float*)bias)[e * DD + col];
  }
  #pragma unroll
  for (int mt = 0; mt < 4; ++mt) {
    int rbase = m0 + wm * 64 + mt * 16 + q * 4;
    #pragma unroll
    for (int r = 0; r < 4; ++r) {
      int row = rbase + r;
      int orow = row;
      if (perm) { orow = perm[row]; if (orow < 0) continue; }
      #pragma unroll
      for (int nt = 0; nt < 4; ++nt) {
        int col = n0 + wn * 64 + nt * 16 + cl;
        float v = acc[mt][nt][r] + bv[nt];
        v = v > 0.0f ? v : 0.0f;
        if (!final_out || isbf) ((u16*)Out)[(size_t)orow * DD + col] = f2bf(v);
        else                    ((float*)Out)[(size_t)orow * DD + col] = v;
      }
    }
  }
}

#undef TILE
#undef STG

extern "C" void kernel_launch(void* const* d_in, const int* in_sizes, int n_in,
                              void* d_out, int out_size, void* d_ws, size_t ws_size,
                              hipStream_t stream) {
  (void)in_sizes; (void)n_in; (void)out_size; (void)ws_size;
  const void* x  = d_in[0];
  const void* W0 = d_in[1];
  const void* b0 = d_in[2];
  const void* W1 = d_in[3];
  const void* b1 = d_in[4];
  const void* W2 = d_in[5];
  const void* b2 = d_in[6];
  const int*  pm = (const int*)d_in[7];

  char* ws  = (char*)d_ws;
  u16*  wt  = (u16*)(ws + OFF_WT);
  u16*  xb  = (u16*)(ws + OFF_XB);   // also reused as h1 after stage0
  u16*  h0  = (u16*)(ws + OFF_H0);
  u16*  h1  = xb;
  int*  p1  = (int*)(ws + OFF_P1);
  int*  p2  = (int*)(ws + OFF_P2);
  int*  meta= (int*)(ws + OFF_META);

  hipLaunchKernelGGL(k_detect, dim3(1),  dim3(256),  0, stream, (const u16*)x, meta);
  hipLaunchKernelGGL(k_route,  dim3(1),  dim3(1024), 0, stream, pm, p1, p2, meta);
  hipLaunchKernelGGL(k_cvtx,   dim3(BB*DD/8/256), dim3(256), 0, stream, x, xb, meta);
  hipLaunchKernelGGL(k_wt,     dim3(7*1024), dim3(256), 0, stream, W0, W1, W2, wt, meta);

  // stage 0: h0 = relu(x @ W0 + b0)            grid 16 n-tiles x 32 m-tiles
  hipLaunchKernelGGL(k_gemm, dim3(16, 32), dim3(512), 0, stream,
                     xb, wt, b0, (const int*)nullptr, (const int*)nullptr, 1,
                     (void*)h0, 0, meta);
  // stage 1: h1 = relu(h0 @ W1[bit0] + b1[bit0]), rows grouped by bit0
  hipLaunchKernelGGL(k_gemm, dim3(16, NP1/256), dim3(512), 0, stream,
                     h0, wt + (size_t)1*DD*DD, b1, p1, meta + 12, 2,
                     (void*)h1, 0, meta);
  // stage 2: y = relu(h1 @ W2[leaf] + b2[leaf]), rows grouped by leaf
  hipLaunchKernelGGL(k_gemm, dim3(16, NP2/256), dim3(512), 0, stream,
                     h1, wt + (size_t)3*DD*DD, b2, p2, meta + 15, 4,
                     d_out, 1, meta);
}